// Round 6
// baseline (745.699 us; speedup 1.0000x reference)
//
#include <hip/hip_runtime.h>
#include <math.h>

#define NT 1024
#define NW (NT / 64)

typedef __attribute__((ext_vector_type(8))) short short8;
typedef __attribute__((ext_vector_type(4))) float f32x4;

// ---- LDS arena byte offsets ----
#define U_OFF     0        // 64 f32
#define IT_OFF    256      // 64 f32
#define B1_OFF    512      // 32 f32
#define RB_OFF    640      // 160 f32
#define PW_OFF    1280     // 32 f32
#define PBI_OFF   1408     // 1 f32
#define X1_OFF    1536     // bf16 [34][34][32] row stride 2192 -> 74528 B
#define X1_STR    2192
#define X2_OFF    76064    // bf16 [18][18][32] stride 1168 -> 21024 B
#define X2_STR    1168
#define T_OFF     76064    // alias over X2 (dead after P2): f32 [4][32][ci32] stride 144
#define X3_OFF    97088    // bf16 [10][10][32] stride 656 -> 6560
#define X3_STR    656
#define X4_OFF    103648   // bf16 [6][6][32] stride 400 -> 2400
#define X4_STR    400
#define X5_OFF    106048   // bf16 [4][4][32] stride 272 -> 1088
#define X5_STR    272
#define X6_OFF    107136   // 32 f32 = 128
#define SMEM_BYTES 107264
// NOTE: all X strides ≡ 16 mod 32 and bases 32-aligned -> the XOR swizzle
// (byte bit4 ^= row bit3) maps logical (row,col,g) chunks injectively to
// physical chunks; producers, halo-zeroing, and readers all apply the SAME
// transform (Round-5 bug: halo zeroing was unswizzled -> holes + races).

__device__ __forceinline__ unsigned short f2bf(float f) {   // RNE f32->bf16
    unsigned int x = __float_as_uint(f);
    x += 0x7fffu + ((x >> 16) & 1u);
    return (unsigned short)(x >> 16);
}

// Zero the halo of an [N][N][32ch] bf16 tensor AT SWIZZLED ADDRESSES:
// rows 0, N-1 (all cols) + cols 0, N-1 of rows 1..N-2; 16B chunks (g=0..3).
template<int N, int STR>
__device__ __forceinline__ void zeroBorderSw(char* smb, int off, int t) {
    const float4 z = make_float4(0.f, 0.f, 0.f, 0.f);
    constexpr int ROWCH = N * 4;                 // 16B chunks per full row
    constexpr int TOT = 2 * ROWCH + (N - 2) * 8;
    for (int k = t; k < TOT; k += NT) {
        int row, col, g;
        if (k < 2 * ROWCH) {
            row = (k < ROWCH) ? 0 : (N - 1);
            const int kk = (k < ROWCH) ? k : k - ROWCH;
            col = kk >> 2; g = kk & 3;
        } else {
            const int j = k - 2 * ROWCH;
            row = 1 + (j >> 3);
            col = ((j >> 2) & 1) ? (N - 1) : 0;
            g = j & 3;
        }
        unsigned addr = (unsigned)(off + row * STR + col * 64 + g * 16);
        addr ^= (unsigned)(((row >> 3) & 1) << 4);   // SAME swizzle as readers
        *(float4*)(smb + addr) = z;
    }
}

// B-frags for mfma_f32_16x16x32_bf16 (VERIFIED mapping, Round 2):
// lane l: col n = l&15 (co = nt*16+n), k = (l>>4)*8 + e.  ws: bf16 [L][tap][co][ci].
__device__ __forceinline__ void loadB16(short8 bfr[16], const unsigned short* __restrict__ wsbf,
                                        const float* __restrict__ rwg, int useWs,
                                        int L, int co, int g) {
    if (useWs) {
        const unsigned short* base = wsbf + L * 16384 + co * 32 + g * 8;
#pragma unroll
        for (int tap = 0; tap < 16; ++tap)
            bfr[tap] = *(const short8*)(base + tap * 1024);
    } else {  // fallback: gather f32 weights from rwg [L][co][ci][tap], convert in regs
#pragma unroll
        for (int tap = 0; tap < 16; ++tap) {
            union { short8 s; unsigned short u[8]; } cv;
#pragma unroll
            for (int e = 0; e < 8; ++e)
                cv.u[e] = f2bf(rwg[((L * 32 + co) * 32 + g * 8 + e) * 16 + tap]);
            bfr[tap] = cv.s;
        }
    }
}

// One conv layer as 16 tap-GEMMs via mfma_f32_16x16x32_bf16 (Round-2-verified
// mappings). A: lane row ml=l&15 -> (p,q), k=(l>>4)*8+e. C/D: col=l&15,
// row=(l>>4)*4+vi. Src/dst bf16 [row][col][32ci], XOR-swizzle byte bit4 ^= row bit3.
template<int PB, int QB, int INS, int OUTS, bool LAST>
__device__ __forceinline__ void conv16(char* smb, int inOff, int outOff,
                                       const short8 bfr[16], float bias) {
    const int t = threadIdx.x;
    const int w = t >> 6, l = t & 63;
    const int n = l & 15, g = l >> 4, nt = w & 1;
    constexpr int MT = (PB * QB + 15) / 16;
    for (int tile = w; tile < 2 * MT; tile += NW) {   // step NW (even) keeps tile&1 == nt
        const int mt = tile >> 1;
        f32x4 acc = {bias, bias, bias, bias};
        const int ml = l & 15;
        const int p = ml % PB;
        const int qq = mt * (16 / PB) + ml / PB;
        const bool valid = (qq < QB);
#pragma unroll
        for (int a = 0; a < 4; ++a)
#pragma unroll
            for (int dj = 0; dj < 4; ++dj) {
                const int row = valid ? (2 * p + a) : 0;   // invalid lanes read halo zeros
                const int col = valid ? (2 * qq + dj) : 0;
                unsigned addr = (unsigned)(inOff + row * INS + col * 64 + g * 16);
                addr ^= (unsigned)(((row >> 3) & 1) << 4);
                short8 af = *(const short8*)(smb + addr);
                acc = __builtin_amdgcn_mfma_f32_16x16x32_bf16(af, bfr[a * 4 + dj], acc, 0, 0, 0);
            }
#pragma unroll
        for (int vi = 0; vi < 4; ++vi) {
            const int mo = g * 4 + vi;
            const int po = mo % PB;
            const int qo = mt * (16 / PB) + mo / PB;
            if (qo < QB) {
                const float v = fmaxf(acc[vi], 0.f);
                if constexpr (LAST) {                 // conv6: mo==0 only; write X6 f32
                    *(float*)(smb + outOff + (nt * 16 + n) * 4) = v;
                } else {
                    const int rowo = po + 1;
                    unsigned addr = (unsigned)(outOff + rowo * OUTS + (qo + 1) * 64 + (nt * 16 + n) * 2);
                    addr ^= (unsigned)(((rowo >> 3) & 1) << 4);
                    *(unsigned short*)(smb + addr) = f2bf(v);
                }
            }
        }
    }
}

// pre-convert rest_w (f32 [L][co][ci][a][dj]) -> d_ws bf16 [L][tap][co][ci]
__global__ void preconv_w(const float* __restrict__ rwg, unsigned short* __restrict__ wsbf) {
    int idx = blockIdx.x * 256 + threadIdx.x;
    if (idx < 81920) {
        int ci = idx & 31, co = (idx >> 5) & 31, tap = (idx >> 10) & 15, L = idx >> 14;
        wsbf[idx] = f2bf(rwg[(((L * 32 + co) * 32 + ci) << 4) + tap]);
    }
}

__global__ void __launch_bounds__(NT, 1)
convncf_main(const int* __restrict__ user, const int* __restrict__ item_pos,
             const int* __restrict__ item_neg,
             const float* __restrict__ uemb, const float* __restrict__ iemb,
             const float* __restrict__ w1g, const float* __restrict__ b1g,
             const float* __restrict__ rwg, const float* __restrict__ rbg,
             const float* __restrict__ pwg, const float* __restrict__ pbg,
             const unsigned short* __restrict__ wsbf, int useWs,
             float* __restrict__ out, int B)
{
    extern __shared__ char smb[];
    float* smf = (float*)smb;
    const int t = threadIdx.x, w = t >> 6, l = t & 63;
    const int co = ((t >> 6) & 1) * 16 + (t & 15);   // this thread's output channel
    const int g = l >> 4;
    const int s = blockIdx.x, branch = blockIdx.y;
    const int uidx = user[s];
    const int iidx = branch ? item_neg[s] : item_pos[s];

    short8 bfr[16];
    loadB16(bfr, wsbf, rwg, useWs, 0, co, g);   // conv2 weights: hide under P0-P2

    // ---- P0: consts + embeddings; zero X1/X3/X4/X5 halos (X2 aliases T -> later) ----
    if (t < 64)        smf[U_OFF/4 + t]        = uemb[(long)uidx * 64 + t];
    else if (t < 128)  smf[IT_OFF/4 + t - 64]  = iemb[(long)iidx * 64 + t - 64];
    else if (t < 160)  smf[B1_OFF/4 + t - 128] = b1g[t - 128];
    else if (t < 320)  smf[RB_OFF/4 + t - 160] = rbg[t - 160];
    else if (t < 352)  smf[PW_OFF/4 + t - 320] = pwg[t - 320];
    else if (t == 352) smf[PBI_OFF/4] = pbg[0];
    zeroBorderSw<34, X1_STR>(smb, X1_OFF, t);
    zeroBorderSw<10, X3_STR>(smb, X3_OFF, t);
    zeroBorderSw<6,  X4_STR>(smb, X4_OFF, t);
    zeroBorderSw<4,  X5_STR>(smb, X5_OFF, t);
    __syncthreads();

    // ---- P1: T[a][j][ci] = sum_dj w1[ci,a,dj] * it_pad[2j-1+dj] ----
    for (int v = t; v < 4096; v += NT) {
        const int ci = v & 31, j = (v >> 5) & 31, a = v >> 10;
        const float4 wv = *(const float4*)(w1g + ci * 16 + a * 4);
        const int c0 = 2 * j - 1;
        const float i0 = (c0 >= 0) ? smf[IT_OFF/4 + c0] : 0.f;
        const float i1 = smf[IT_OFF/4 + c0 + 1];
        const float i2 = smf[IT_OFF/4 + c0 + 2];
        const float i3 = (c0 + 3 < 64) ? smf[IT_OFF/4 + c0 + 3] : 0.f;
        float acc = wv.x * i0;
        acc = fmaf(wv.y, i1, acc);
        acc = fmaf(wv.z, i2, acc);
        acc = fmaf(wv.w, i3, acc);
        *(float*)(smb + T_OFF + (a * 32 + j) * 144 + ci * 4) = acc;
    }
    __syncthreads();

    // ---- P2: X1 interior (bf16, swizzled; covers rows/cols 1..32 fully) ----
    for (int v = t; v < 4096; v += NT) {
        const int i = v & 31, j = (v >> 5) & 31, cg = v >> 10;
        float acc[8];
        {
            const float* b1p = smf + B1_OFF/4 + cg * 8;
#pragma unroll
            for (int e = 0; e < 8; ++e) acc[e] = b1p[e];
        }
#pragma unroll
        for (int a = 0; a < 4; ++a) {
            const int m = 2 * i - 1 + a;
            const float uv = (m >= 0 && m < 64) ? smf[U_OFF/4 + m] : 0.f;
            const float* tp = (const float*)(smb + T_OFF + (a * 32 + j) * 144 + cg * 32);
            const float4 t0 = *(const float4*)tp;
            const float4 t1 = *(const float4*)(tp + 4);
            acc[0] = fmaf(uv, t0.x, acc[0]); acc[1] = fmaf(uv, t0.y, acc[1]);
            acc[2] = fmaf(uv, t0.z, acc[2]); acc[3] = fmaf(uv, t0.w, acc[3]);
            acc[4] = fmaf(uv, t1.x, acc[4]); acc[5] = fmaf(uv, t1.y, acc[5]);
            acc[6] = fmaf(uv, t1.z, acc[6]); acc[7] = fmaf(uv, t1.w, acc[7]);
        }
        union { short8 sv; unsigned short u[8]; } cv;
#pragma unroll
        for (int e = 0; e < 8; ++e) cv.u[e] = f2bf(fmaxf(acc[e], 0.f));
        unsigned addr = (unsigned)(X1_OFF + (i + 1) * X1_STR + (j + 1) * 64 + cg * 16);
        addr ^= (unsigned)((((i + 1) >> 3) & 1) << 4);
        *(short8*)(smb + addr) = cv.sv;
    }
    __syncthreads();

    // ---- P3: conv2; X2 halo zeroed concurrently (disjoint PHYSICAL chunks now
    //      that both use the same injective swizzle); prefetch B(L1) ----
    zeroBorderSw<18, X2_STR>(smb, X2_OFF, t);
    conv16<16, 16, X1_STR, X2_STR, false>(smb, X1_OFF, X2_OFF, bfr, smf[RB_OFF/4 + co]);
    loadB16(bfr, wsbf, rwg, useWs, 1, co, g);
    __syncthreads();

    conv16<8, 8, X2_STR, X3_STR, false>(smb, X2_OFF, X3_OFF, bfr, smf[RB_OFF/4 + 32 + co]);
    loadB16(bfr, wsbf, rwg, useWs, 2, co, g);
    __syncthreads();

    conv16<4, 4, X3_STR, X4_STR, false>(smb, X3_OFF, X4_OFF, bfr, smf[RB_OFF/4 + 64 + co]);
    loadB16(bfr, wsbf, rwg, useWs, 3, co, g);
    __syncthreads();

    conv16<2, 2, X4_STR, X5_STR, false>(smb, X4_OFF, X5_OFF, bfr, smf[RB_OFF/4 + 96 + co]);
    loadB16(bfr, wsbf, rwg, useWs, 4, co, g);
    __syncthreads();

    conv16<1, 1, X5_STR, 0, true>(smb, X5_OFF, X6_OFF, bfr, smf[RB_OFF/4 + 128 + co]);
    __syncthreads();

    // ---- head: wave 0 dot(X6, pw) + sigmoid ----
    if (w == 0) {
        float v = (l < 32) ? smf[X6_OFF/4 + l] * smf[PW_OFF/4 + l] : 0.f;
#pragma unroll
        for (int d = 32; d >= 1; d >>= 1) v += __shfl_xor(v, d, 64);
        if (l == 0) {
            const float z = smf[PBI_OFF/4] + v;
            out[branch * B + s] = 1.f / (1.f + expf(-z));
        }
    }
}

extern "C" void kernel_launch(void* const* d_in, const int* in_sizes, int n_in,
                              void* d_out, int out_size, void* d_ws, size_t ws_size,
                              hipStream_t stream) {
    const int*   user     = (const int*)d_in[0];
    const int*   item_pos = (const int*)d_in[1];
    const int*   item_neg = (const int*)d_in[2];
    const float* uemb     = (const float*)d_in[3];
    const float* iemb     = (const float*)d_in[4];
    const float* w1       = (const float*)d_in[5];
    const float* b1       = (const float*)d_in[6];
    const float* rw       = (const float*)d_in[7];
    const float* rb       = (const float*)d_in[8];
    const float* pw       = (const float*)d_in[9];
    const float* pb       = (const float*)d_in[10];
    float* out = (float*)d_out;
    const int B = in_sizes[0];   // 4096

    const int useWs = (ws_size >= 81920u * sizeof(unsigned short)) ? 1 : 0;
    unsigned short* wsbf = (unsigned short*)d_ws;
    if (useWs)
        preconv_w<<<dim3(320), dim3(256), 0, stream>>>(rw, wsbf);

    (void)hipFuncSetAttribute((const void*)convncf_main,
                              hipFuncAttributeMaxDynamicSharedMemorySize, SMEM_BYTES);
    dim3 grid(B, 2);
    convncf_main<<<grid, NT, SMEM_BYTES, stream>>>(
        user, item_pos, item_neg, uemb, iemb, w1, b1, rw, rb, pw, pb,
        wsbf, useWs, out, B);
}

// Round 7
// 588.213 us; speedup vs baseline: 1.2677x; 1.2677x over previous
//
#include <hip/hip_runtime.h>
#include <math.h>

#define NT 512
#define NW 8

typedef __attribute__((ext_vector_type(8))) short short8;
typedef __attribute__((ext_vector_type(4))) float f32x4;

// ---- LDS arena byte offsets (total 69,664 B -> 2 blocks/CU) ----
#define U_OFF    0        // 64 f32
#define IT_OFF   256      // 64 f32
#define B1_OFF   512      // 32 f32
#define RB_OFF   640      // 160 f32
#define PW_OFF   1280     // 32 f32
#define PBI_OFF  1408     // 1 f32
#define ZP_OFF   1424     // 64 B zero page (predicated out-of-range reads land here)
#define X1_OFF   1536     // bf16 [17][32][32] stride 2064 -> 35088 (two-half strip of conv1 out)
#define X1_STR   2064
#define T_OFF    36624    // f32 [4][32][ci32] stride 128 -> 16384 (reads are broadcast; no pad)
#define X2_OFF   53008    // bf16 [16][16][32] stride 1040 -> 16640
#define X2_STR   1040
#define X3_OFF   X1_OFF   // alias over X1 (dead after conv2b): bf16 [8][8][32] stride 528
#define X3_STR   528
#define X4_OFF   (X1_OFF + 4224)   // bf16 [4][4][32] stride 272 -> 1088
#define X4_STR   272
#define X5_OFF   (X1_OFF + 5312)   // bf16 [2][2][32] stride 144 -> 288
#define X5_STR   144
#define X6_OFF   (X1_OFF + 5600)   // 32 f32 = 128
#define SMEM_BYTES 69664
// All X strides ≡ 16 mod 128; every X access applies byte_bit4 ^= buffer_row_bit3.
// Halos are GONE: out-of-range taps read the zero page (uniform addr -> broadcast).

__device__ __forceinline__ unsigned short f2bf(float f) {   // RNE f32->bf16
    unsigned int x = __float_as_uint(f);
    x += 0x7fffu + ((x >> 16) & 1u);
    return (unsigned short)(x >> 16);
}

// B-frags for mfma_f32_16x16x32_bf16 (VERIFIED mapping, Round 2):
// lane l: col n=l&15 (co = nt*16+n), k = (l>>4)*8 + e.  ws: bf16 [L][tap][co][ci].
__device__ __forceinline__ void loadB16(short8 bfr[16], const unsigned short* __restrict__ wsbf,
                                        const float* __restrict__ rwg, int useWs,
                                        int L, int co, int g) {
    if (useWs) {
        const unsigned short* base = wsbf + L * 16384 + co * 32 + g * 8;
#pragma unroll
        for (int tap = 0; tap < 16; ++tap)
            bfr[tap] = *(const short8*)(base + tap * 1024);
    } else {  // fallback: gather f32 weights from rwg [L][co][ci][tap], convert in regs
#pragma unroll
        for (int tap = 0; tap < 16; ++tap) {
            union { short8 s; unsigned short u[8]; } cv;
#pragma unroll
            for (int e = 0; e < 8; ++e)
                cv.u[e] = f2bf(rwg[((L * 32 + co) * 32 + g * 8 + e) * 16 + tap]);
            bfr[tap] = cv.s;
        }
    }
}

// One conv layer as 16 tap-GEMMs via mfma_f32_16x16x32_bf16 (Round-2-verified
// mappings). Output PH x QW spatial block (rows offset by p0), m = q*PH + p.
// Input: logical NIN x NIN halo-free tensor; buffer row = logical row - shift.
// Out-of-range taps read the zero page. All addrs swizzled: bit4 ^= row bit3.
template<int PH, int QW, int NIN, int INS, int OUTS, bool LAST>
__device__ __forceinline__ void convL(char* smb, int inOff, int outOff,
                                      const short8 bfr[16], float bias,
                                      int p0, int shift) {
    const int t = threadIdx.x;
    const int w = t >> 6, l = t & 63;
    const int n = l & 15, g = l >> 4, nt = w & 1;
    constexpr int M = PH * QW;
    constexpr int MT = (M + 15) / 16;
    for (int tile = w; tile < 2 * MT; tile += NW) {   // step NW (even) keeps tile&1 == nt
        const int mt = tile >> 1;
        f32x4 acc = {bias, bias, bias, bias};
        const int m = mt * 16 + (l & 15);
        const int mm = (m < M) ? m : 0;
        const int p = mm % PH, q = mm / PH;
#pragma unroll
        for (int a = 0; a < 4; ++a)
#pragma unroll
            for (int dj = 0; dj < 4; ++dj) {
                const int row = 2 * (p0 + p) + a - 1;       // logical coords
                const int col = 2 * q + dj - 1;
                const bool ok = (m < M) && ((unsigned)row < (unsigned)NIN)
                                        && ((unsigned)col < (unsigned)NIN);
                const int rb = row - shift;                  // buffer row
                unsigned addr = (unsigned)(inOff + rb * INS + col * 64 + g * 16);
                addr ^= (unsigned)(((rb >> 3) & 1) << 4);
                addr = ok ? addr : (unsigned)(ZP_OFF + g * 16);
                short8 af = *(const short8*)(smb + addr);
                acc = __builtin_amdgcn_mfma_f32_16x16x32_bf16(af, bfr[a * 4 + dj], acc, 0, 0, 0);
            }
#pragma unroll
        for (int vi = 0; vi < 4; ++vi) {                     // D: col=l&15, row=g*4+vi
            const int mo = mt * 16 + g * 4 + vi;
            if (mo < M) {
                const float v = fmaxf(acc[vi], 0.f);
                if constexpr (LAST) {                        // M==1: only mo==0 lands here
                    *(float*)(smb + outOff + (nt * 16 + n) * 4) = v;
                } else {
                    const int po = mo % PH + p0, qo = mo / PH;
                    unsigned addr = (unsigned)(outOff + po * OUTS + qo * 64 + (nt * 16 + n) * 2);
                    addr ^= (unsigned)(((po >> 3) & 1) << 4);
                    *(unsigned short*)(smb + addr) = f2bf(v);
                }
            }
        }
    }
}

// pre-convert rest_w (f32 [L][co][ci][a][dj]) -> d_ws bf16 [L][tap][co][ci]
__global__ void preconv_w(const float* __restrict__ rwg, unsigned short* __restrict__ wsbf) {
    int idx = blockIdx.x * 256 + threadIdx.x;
    if (idx < 81920) {
        int ci = idx & 31, co = (idx >> 5) & 31, tap = (idx >> 10) & 15, L = idx >> 14;
        wsbf[idx] = f2bf(rwg[(((L * 32 + co) * 32 + ci) << 4) + tap]);
    }
}

__global__ void __launch_bounds__(NT, 4)
convncf_main(const int* __restrict__ user, const int* __restrict__ item_pos,
             const int* __restrict__ item_neg,
             const float* __restrict__ uemb, const float* __restrict__ iemb,
             const float* __restrict__ w1g, const float* __restrict__ b1g,
             const float* __restrict__ rwg, const float* __restrict__ rbg,
             const float* __restrict__ pwg, const float* __restrict__ pbg,
             const unsigned short* __restrict__ wsbf, int useWs,
             float* __restrict__ out, int B)
{
    extern __shared__ char smb[];
    float* smf = (float*)smb;
    const int t = threadIdx.x, w = t >> 6, l = t & 63;
    const int co = ((t >> 6) & 1) * 16 + (t & 15);   // this thread's output channel
    const int g = l >> 4;
    const int s = blockIdx.x, branch = blockIdx.y;
    const int uidx = user[s];
    const int iidx = branch ? item_neg[s] : item_pos[s];

    short8 bfr[16];
    loadB16(bfr, wsbf, rwg, useWs, 0, co, g);   // conv2 weights: hide under P0-P2a

    // ---- P0: consts + embeddings + zero page (no halo zeroing exists anymore) ----
    if (t < 64)        smf[U_OFF/4 + t]        = uemb[(long)uidx * 64 + t];
    else if (t < 128)  smf[IT_OFF/4 + t - 64]  = iemb[(long)iidx * 64 + t - 64];
    else if (t < 160)  smf[B1_OFF/4 + t - 128] = b1g[t - 128];
    else if (t < 320)  smf[RB_OFF/4 + t - 160] = rbg[t - 160];
    else if (t < 352)  smf[PW_OFF/4 + t - 320] = pwg[t - 320];
    else if (t == 352) smf[PBI_OFF/4] = pbg[0];
    if (t < 4) *(float4*)(smb + ZP_OFF + t * 16) = make_float4(0.f, 0.f, 0.f, 0.f);
    __syncthreads();

    // ---- P1: T[a][j][ci] = sum_dj w1[ci,a,dj] * it_pad[2j-1+dj] ----
    for (int v = t; v < 4096; v += NT) {
        const int ci = v & 31, j = (v >> 5) & 31, a = v >> 10;
        const float4 wv = *(const float4*)(w1g + ci * 16 + a * 4);
        const int c0 = 2 * j - 1;
        const float i0 = (c0 >= 0) ? smf[IT_OFF/4 + c0] : 0.f;
        const float i1 = smf[IT_OFF/4 + c0 + 1];
        const float i2 = smf[IT_OFF/4 + c0 + 2];
        const float i3 = (c0 + 3 < 64) ? smf[IT_OFF/4 + c0 + 3] : 0.f;
        float acc = wv.x * i0;
        acc = fmaf(wv.y, i1, acc);
        acc = fmaf(wv.z, i2, acc);
        acc = fmaf(wv.w, i3, acc);
        *(float*)(smb + T_OFF + (a * 32 + j) * 128 + ci * 4) = acc;
    }
    __syncthreads();

    // ---- two half-strips: build X1 rows, conv2 on matching output rows ----
#pragma unroll 1
    for (int h = 0; h < 2; ++h) {
        const int shift = 15 * h;
        // P2(h): X1buf rows rl=0..16 hold logical rows r=rl+shift (bf16, swizzled)
        for (int v = t; v < 2176; v += NT) {
            const int cg = v & 3, j = (v >> 2) & 31, rl = v >> 7;   // rl 0..16
            const int r = rl + shift;
            float acc[8];
            {
                const float* b1p = smf + B1_OFF/4 + cg * 8;
#pragma unroll
                for (int e = 0; e < 8; ++e) acc[e] = b1p[e];
            }
#pragma unroll
            for (int a = 0; a < 4; ++a) {
                const int m = 2 * r - 1 + a;
                const float uv = (m >= 0 && m < 64) ? smf[U_OFF/4 + m] : 0.f;
                const float* tp = (const float*)(smb + T_OFF + (a * 32 + j) * 128 + cg * 32);
                const float4 t0 = *(const float4*)tp;
                const float4 t1 = *(const float4*)(tp + 4);
                acc[0] = fmaf(uv, t0.x, acc[0]); acc[1] = fmaf(uv, t0.y, acc[1]);
                acc[2] = fmaf(uv, t0.z, acc[2]); acc[3] = fmaf(uv, t0.w, acc[3]);
                acc[4] = fmaf(uv, t1.x, acc[4]); acc[5] = fmaf(uv, t1.y, acc[5]);
                acc[6] = fmaf(uv, t1.z, acc[6]); acc[7] = fmaf(uv, t1.w, acc[7]);
            }
            union { short8 sv; unsigned short u[8]; } cv;
#pragma unroll
            for (int e = 0; e < 8; ++e) cv.u[e] = f2bf(fmaxf(acc[e], 0.f));
            unsigned addr = (unsigned)(X1_OFF + rl * X1_STR + j * 64 + cg * 16);
            addr ^= (unsigned)(((rl >> 3) & 1) << 4);
            *(short8*)(smb + addr) = cv.sv;
        }
        __syncthreads();

        // conv2(h): output rows p0..p0+7, all 16 cols
        convL<8, 16, 32, X1_STR, X2_STR, false>(smb, X1_OFF, X2_OFF, bfr,
                                                smf[RB_OFF/4 + co], 8 * h, shift);
        if (h == 1) loadB16(bfr, wsbf, rwg, useWs, 1, co, g);   // L0 frags dead now
        __syncthreads();
    }

    // ---- conv3..6; next layer's B-frags load before each barrier ----
    convL<8, 8, 16, X2_STR, X3_STR, false>(smb, X2_OFF, X3_OFF, bfr, smf[RB_OFF/4 + 32 + co], 0, 0);
    loadB16(bfr, wsbf, rwg, useWs, 2, co, g);
    __syncthreads();

    convL<4, 4, 8, X3_STR, X4_STR, false>(smb, X3_OFF, X4_OFF, bfr, smf[RB_OFF/4 + 64 + co], 0, 0);
    loadB16(bfr, wsbf, rwg, useWs, 3, co, g);
    __syncthreads();

    convL<2, 2, 4, X4_STR, X5_STR, false>(smb, X4_OFF, X5_OFF, bfr, smf[RB_OFF/4 + 96 + co], 0, 0);
    loadB16(bfr, wsbf, rwg, useWs, 4, co, g);
    __syncthreads();

    convL<1, 1, 2, X5_STR, 0, true>(smb, X5_OFF, X6_OFF, bfr, smf[RB_OFF/4 + 128 + co], 0, 0);
    __syncthreads();

    // ---- head: wave 0 dot(X6, pw) + sigmoid ----
    if (w == 0) {
        float v = (l < 32) ? smf[X6_OFF/4 + l] * smf[PW_OFF/4 + l] : 0.f;
#pragma unroll
        for (int d = 32; d >= 1; d >>= 1) v += __shfl_xor(v, d, 64);
        if (l == 0) {
            const float z = smf[PBI_OFF/4] + v;
            out[branch * B + s] = 1.f / (1.f + expf(-z));
        }
    }
}

extern "C" void kernel_launch(void* const* d_in, const int* in_sizes, int n_in,
                              void* d_out, int out_size, void* d_ws, size_t ws_size,
                              hipStream_t stream) {
    const int*   user     = (const int*)d_in[0];
    const int*   item_pos = (const int*)d_in[1];
    const int*   item_neg = (const int*)d_in[2];
    const float* uemb     = (const float*)d_in[3];
    const float* iemb     = (const float*)d_in[4];
    const float* w1       = (const float*)d_in[5];
    const float* b1       = (const float*)d_in[6];
    const float* rw       = (const float*)d_in[7];
    const float* rb       = (const float*)d_in[8];
    const float* pw       = (const float*)d_in[9];
    const float* pb       = (const float*)d_in[10];
    float* out = (float*)d_out;
    const int B = in_sizes[0];   // 4096

    const int useWs = (ws_size >= 81920u * sizeof(unsigned short)) ? 1 : 0;
    unsigned short* wsbf = (unsigned short*)d_ws;
    if (useWs)
        preconv_w<<<dim3(320), dim3(256), 0, stream>>>(rw, wsbf);

    (void)hipFuncSetAttribute((const void*)convncf_main,
                              hipFuncAttributeMaxDynamicSharedMemorySize, SMEM_BYTES);
    dim3 grid(B, 2);
    convncf_main<<<grid, NT, SMEM_BYTES, stream>>>(
        user, item_pos, item_neg, uemb, iemb, w1, b1, rw, rb, pw, pb,
        wsbf, useWs, out, B);
}

// Round 8
// 562.106 us; speedup vs baseline: 1.3266x; 1.0464x over previous
//
#include <hip/hip_runtime.h>
#include <math.h>

#define NT 512
#define NW 8

typedef __attribute__((ext_vector_type(8))) short short8;
typedef __attribute__((ext_vector_type(4))) float f32x4;

// ---- LDS arena byte offsets (total 69,664 B -> 2 blocks/CU) ----
#define U_OFF    0        // 64 f32
#define IT_OFF   256      // 64 f32
#define B1_OFF   512      // 32 f32
#define RB_OFF   640      // 160 f32
#define PW_OFF   1280     // 32 f32
#define PBI_OFF  1408     // 1 f32
#define ZP_OFF   1424     // 64 B zero page (predicated out-of-range reads land here)
#define X1_OFF   1536     // bf16 [17][32][32] stride 2064 -> 35088 (two-half strip of conv1 out)
#define X1_STR   2064
#define T_OFF    36624    // f32 [4][32][ci32] stride 128 -> 16384 (reads are broadcast; no pad)
#define X2_OFF   53008    // bf16 [16][16][32] stride 1040 -> 16640
#define X2_STR   1040
#define X3_OFF   X1_OFF   // alias over X1 (dead after conv2b): bf16 [8][8][32] stride 528
#define X3_STR   528
#define X4_OFF   (X1_OFF + 4224)   // bf16 [4][4][32] stride 272 -> 1088
#define X4_STR   272
#define X5_OFF   (X1_OFF + 5312)   // bf16 [2][2][32] stride 144 -> 288
#define X5_STR   144
#define X6_OFF   (X1_OFF + 5600)   // 32 f32 = 128
#define SMEM_BYTES 69664
// All X strides ≡ 16 mod 128; every X access applies byte_bit4 ^= buffer_row_bit3.
// Halos are GONE: out-of-range taps read the zero page (uniform addr -> broadcast).
// launch_bounds(NT,2): R7's (NT,4) capped VGPR at 64 -> bfr[16] spilled -> 1.1 GB
// HBM scratch traffic. 92-110 VGPR ≤ 128 still allows 16 waves/CU (2 blocks).

__device__ __forceinline__ unsigned short f2bf(float f) {   // RNE f32->bf16
    unsigned int x = __float_as_uint(f);
    x += 0x7fffu + ((x >> 16) & 1u);
    return (unsigned short)(x >> 16);
}

// B-frags for mfma_f32_16x16x32_bf16 (VERIFIED mapping, Round 2):
// lane l: col n=l&15 (co = nt*16+n), k = (l>>4)*8 + e.  ws: bf16 [L][tap][co][ci].
__device__ __forceinline__ void loadB16(short8 bfr[16], const unsigned short* __restrict__ wsbf,
                                        const float* __restrict__ rwg, int useWs,
                                        int L, int co, int g) {
    if (useWs) {
        const unsigned short* base = wsbf + L * 16384 + co * 32 + g * 8;
#pragma unroll
        for (int tap = 0; tap < 16; ++tap)
            bfr[tap] = *(const short8*)(base + tap * 1024);
    } else {  // fallback: gather f32 weights from rwg [L][co][ci][tap], convert in regs
#pragma unroll
        for (int tap = 0; tap < 16; ++tap) {
            union { short8 s; unsigned short u[8]; } cv;
#pragma unroll
            for (int e = 0; e < 8; ++e)
                cv.u[e] = f2bf(rwg[((L * 32 + co) * 32 + g * 8 + e) * 16 + tap]);
            bfr[tap] = cv.s;
        }
    }
}

// One conv layer as 16 tap-GEMMs via mfma_f32_16x16x32_bf16 (Round-2-verified
// mappings). Output PH x QW spatial block (rows offset by p0), m = q*PH + p.
// Input: logical NIN x NIN halo-free tensor; buffer row = logical row - shift.
// Out-of-range taps read the zero page. All addrs swizzled: bit4 ^= row bit3.
template<int PH, int QW, int NIN, int INS, int OUTS, bool LAST>
__device__ __forceinline__ void convL(char* smb, int inOff, int outOff,
                                      const short8 bfr[16], float bias,
                                      int p0, int shift) {
    const int t = threadIdx.x;
    const int w = t >> 6, l = t & 63;
    const int n = l & 15, g = l >> 4, nt = w & 1;
    constexpr int M = PH * QW;
    constexpr int MT = (M + 15) / 16;
    for (int tile = w; tile < 2 * MT; tile += NW) {   // step NW (even) keeps tile&1 == nt
        const int mt = tile >> 1;
        f32x4 acc = {bias, bias, bias, bias};
        const int m = mt * 16 + (l & 15);
        const int mm = (m < M) ? m : 0;
        const int p = mm % PH, q = mm / PH;
#pragma unroll
        for (int a = 0; a < 4; ++a)
#pragma unroll
            for (int dj = 0; dj < 4; ++dj) {
                const int row = 2 * (p0 + p) + a - 1;       // logical coords
                const int col = 2 * q + dj - 1;
                const bool ok = (m < M) && ((unsigned)row < (unsigned)NIN)
                                        && ((unsigned)col < (unsigned)NIN);
                const int rb = row - shift;                  // buffer row
                unsigned addr = (unsigned)(inOff + rb * INS + col * 64 + g * 16);
                addr ^= (unsigned)(((rb >> 3) & 1) << 4);
                addr = ok ? addr : (unsigned)(ZP_OFF + g * 16);
                short8 af = *(const short8*)(smb + addr);
                acc = __builtin_amdgcn_mfma_f32_16x16x32_bf16(af, bfr[a * 4 + dj], acc, 0, 0, 0);
            }
#pragma unroll
        for (int vi = 0; vi < 4; ++vi) {                     // D: col=l&15, row=g*4+vi
            const int mo = mt * 16 + g * 4 + vi;
            if (mo < M) {
                const float v = fmaxf(acc[vi], 0.f);
                if constexpr (LAST) {                        // M==1: only mo==0 lands here
                    *(float*)(smb + outOff + (nt * 16 + n) * 4) = v;
                } else {
                    const int po = mo % PH + p0, qo = mo / PH;
                    unsigned addr = (unsigned)(outOff + po * OUTS + qo * 64 + (nt * 16 + n) * 2);
                    addr ^= (unsigned)(((po >> 3) & 1) << 4);
                    *(unsigned short*)(smb + addr) = f2bf(v);
                }
            }
        }
    }
}

// pre-convert rest_w (f32 [L][co][ci][a][dj]) -> d_ws bf16 [L][tap][co][ci]
__global__ void preconv_w(const float* __restrict__ rwg, unsigned short* __restrict__ wsbf) {
    int idx = blockIdx.x * 256 + threadIdx.x;
    if (idx < 81920) {
        int ci = idx & 31, co = (idx >> 5) & 31, tap = (idx >> 10) & 15, L = idx >> 14;
        wsbf[idx] = f2bf(rwg[(((L * 32 + co) * 32 + ci) << 4) + tap]);
    }
}

__global__ void __launch_bounds__(NT, 2)
convncf_main(const int* __restrict__ user, const int* __restrict__ item_pos,
             const int* __restrict__ item_neg,
             const float* __restrict__ uemb, const float* __restrict__ iemb,
             const float* __restrict__ w1g, const float* __restrict__ b1g,
             const float* __restrict__ rwg, const float* __restrict__ rbg,
             const float* __restrict__ pwg, const float* __restrict__ pbg,
             const unsigned short* __restrict__ wsbf, int useWs,
             float* __restrict__ out, int B)
{
    extern __shared__ char smb[];
    float* smf = (float*)smb;
    const int t = threadIdx.x, w = t >> 6, l = t & 63;
    const int co = ((t >> 6) & 1) * 16 + (t & 15);   // this thread's output channel
    const int g = l >> 4;
    const int s = blockIdx.x, branch = blockIdx.y;
    const int uidx = user[s];
    const int iidx = branch ? item_neg[s] : item_pos[s];

    short8 bfr[16];
    loadB16(bfr, wsbf, rwg, useWs, 0, co, g);   // conv2 weights: hide under P0-P2a

    // ---- P0: consts + embeddings + zero page (no halo zeroing exists anymore) ----
    if (t < 64)        smf[U_OFF/4 + t]        = uemb[(long)uidx * 64 + t];
    else if (t < 128)  smf[IT_OFF/4 + t - 64]  = iemb[(long)iidx * 64 + t - 64];
    else if (t < 160)  smf[B1_OFF/4 + t - 128] = b1g[t - 128];
    else if (t < 320)  smf[RB_OFF/4 + t - 160] = rbg[t - 160];
    else if (t < 352)  smf[PW_OFF/4 + t - 320] = pwg[t - 320];
    else if (t == 352) smf[PBI_OFF/4] = pbg[0];
    if (t < 4) *(float4*)(smb + ZP_OFF + t * 16) = make_float4(0.f, 0.f, 0.f, 0.f);
    __syncthreads();

    // ---- P1: T[a][j][ci] = sum_dj w1[ci,a,dj] * it_pad[2j-1+dj] ----
    for (int v = t; v < 4096; v += NT) {
        const int ci = v & 31, j = (v >> 5) & 31, a = v >> 10;
        const float4 wv = *(const float4*)(w1g + ci * 16 + a * 4);
        const int c0 = 2 * j - 1;
        const float i0 = (c0 >= 0) ? smf[IT_OFF/4 + c0] : 0.f;
        const float i1 = smf[IT_OFF/4 + c0 + 1];
        const float i2 = smf[IT_OFF/4 + c0 + 2];
        const float i3 = (c0 + 3 < 64) ? smf[IT_OFF/4 + c0 + 3] : 0.f;
        float acc = wv.x * i0;
        acc = fmaf(wv.y, i1, acc);
        acc = fmaf(wv.z, i2, acc);
        acc = fmaf(wv.w, i3, acc);
        *(float*)(smb + T_OFF + (a * 32 + j) * 128 + ci * 4) = acc;
    }
    __syncthreads();

    // ---- two half-strips: build X1 rows, conv2 on matching output rows ----
#pragma unroll 1
    for (int h = 0; h < 2; ++h) {
        const int shift = 15 * h;
        // P2(h): X1buf rows rl=0..16 hold logical rows r=rl+shift (bf16, swizzled)
        for (int v = t; v < 2176; v += NT) {
            const int cg = v & 3, j = (v >> 2) & 31, rl = v >> 7;   // rl 0..16
            const int r = rl + shift;
            float acc[8];
            {
                const float* b1p = smf + B1_OFF/4 + cg * 8;
#pragma unroll
                for (int e = 0; e < 8; ++e) acc[e] = b1p[e];
            }
#pragma unroll
            for (int a = 0; a < 4; ++a) {
                const int m = 2 * r - 1 + a;
                const float uv = (m >= 0 && m < 64) ? smf[U_OFF/4 + m] : 0.f;
                const float* tp = (const float*)(smb + T_OFF + (a * 32 + j) * 128 + cg * 32);
                const float4 t0 = *(const float4*)tp;
                const float4 t1 = *(const float4*)(tp + 4);
                acc[0] = fmaf(uv, t0.x, acc[0]); acc[1] = fmaf(uv, t0.y, acc[1]);
                acc[2] = fmaf(uv, t0.z, acc[2]); acc[3] = fmaf(uv, t0.w, acc[3]);
                acc[4] = fmaf(uv, t1.x, acc[4]); acc[5] = fmaf(uv, t1.y, acc[5]);
                acc[6] = fmaf(uv, t1.z, acc[6]); acc[7] = fmaf(uv, t1.w, acc[7]);
            }
            union { short8 sv; unsigned short u[8]; } cv;
#pragma unroll
            for (int e = 0; e < 8; ++e) cv.u[e] = f2bf(fmaxf(acc[e], 0.f));
            unsigned addr = (unsigned)(X1_OFF + rl * X1_STR + j * 64 + cg * 16);
            addr ^= (unsigned)(((rl >> 3) & 1) << 4);
            *(short8*)(smb + addr) = cv.sv;
        }
        __syncthreads();

        // conv2(h): output rows p0..p0+7, all 16 cols
        convL<8, 16, 32, X1_STR, X2_STR, false>(smb, X1_OFF, X2_OFF, bfr,
                                                smf[RB_OFF/4 + co], 8 * h, shift);
        if (h == 1) loadB16(bfr, wsbf, rwg, useWs, 1, co, g);   // L0 frags dead now
        __syncthreads();
    }

    // ---- conv3..6; next layer's B-frags load before each barrier ----
    convL<8, 8, 16, X2_STR, X3_STR, false>(smb, X2_OFF, X3_OFF, bfr, smf[RB_OFF/4 + 32 + co], 0, 0);
    loadB16(bfr, wsbf, rwg, useWs, 2, co, g);
    __syncthreads();

    convL<4, 4, 8, X3_STR, X4_STR, false>(smb, X3_OFF, X4_OFF, bfr, smf[RB_OFF/4 + 64 + co], 0, 0);
    loadB16(bfr, wsbf, rwg, useWs, 3, co, g);
    __syncthreads();

    convL<2, 2, 4, X4_STR, X5_STR, false>(smb, X4_OFF, X5_OFF, bfr, smf[RB_OFF/4 + 96 + co], 0, 0);
    loadB16(bfr, wsbf, rwg, useWs, 4, co, g);
    __syncthreads();

    convL<1, 1, 2, X5_STR, 0, true>(smb, X5_OFF, X6_OFF, bfr, smf[RB_OFF/4 + 128 + co], 0, 0);
    __syncthreads();

    // ---- head: wave 0 dot(X6, pw) + sigmoid ----
    if (w == 0) {
        float v = (l < 32) ? smf[X6_OFF/4 + l] * smf[PW_OFF/4 + l] : 0.f;
#pragma unroll
        for (int d = 32; d >= 1; d >>= 1) v += __shfl_xor(v, d, 64);
        if (l == 0) {
            const float z = smf[PBI_OFF/4] + v;
            out[branch * B + s] = 1.f / (1.f + expf(-z));
        }
    }
}

extern "C" void kernel_launch(void* const* d_in, const int* in_sizes, int n_in,
                              void* d_out, int out_size, void* d_ws, size_t ws_size,
                              hipStream_t stream) {
    const int*   user     = (const int*)d_in[0];
    const int*   item_pos = (const int*)d_in[1];
    const int*   item_neg = (const int*)d_in[2];
    const float* uemb     = (const float*)d_in[3];
    const float* iemb     = (const float*)d_in[4];
    const float* w1       = (const float*)d_in[5];
    const float* b1       = (const float*)d_in[6];
    const float* rw       = (const float*)d_in[7];
    const float* rb       = (const float*)d_in[8];
    const float* pw       = (const float*)d_in[9];
    const float* pb       = (const float*)d_in[10];
    float* out = (float*)d_out;
    const int B = in_sizes[0];   // 4096

    const int useWs = (ws_size >= 81920u * sizeof(unsigned short)) ? 1 : 0;
    unsigned short* wsbf = (unsigned short*)d_ws;
    if (useWs)
        preconv_w<<<dim3(320), dim3(256), 0, stream>>>(rw, wsbf);

    (void)hipFuncSetAttribute((const void*)convncf_main,
                              hipFuncAttributeMaxDynamicSharedMemorySize, SMEM_BYTES);
    dim3 grid(B, 2);
    convncf_main<<<grid, NT, SMEM_BYTES, stream>>>(
        user, item_pos, item_neg, uemb, iemb, w1, b1, rw, rb, pw, pb,
        wsbf, useWs, out, B);
}

// Round 9
// 376.139 us; speedup vs baseline: 1.9825x; 1.4944x over previous
//
#include <hip/hip_runtime.h>
#include <math.h>

#define NT 256
#define NW 4

typedef __attribute__((ext_vector_type(8))) short short8;
typedef __attribute__((ext_vector_type(4))) float f32x4;

// ---- LDS arena byte offsets (total 69,664 B; 2 blocks/CU by LDS) ----
#define U_OFF    0        // 64 f32
#define IT_OFF   256      // 64 f32
#define B1_OFF   512      // 32 f32
#define RB_OFF   640      // 160 f32
#define PW_OFF   1280     // 32 f32
#define PBI_OFF  1408     // 1 f32
#define ZP_OFF   1424     // 64 B zero page (predicated out-of-range reads land here)
#define X1_OFF   1536     // bf16 [17][32][32] stride 2064 -> 35088 (two-half strip of conv1 out)
#define X1_STR   2064
#define T_OFF    36624    // f32 [4][32][ci32] stride 128 -> 16384 (reads are broadcast; no pad)
#define X2_OFF   53008    // bf16 [16][16][32] stride 1040 -> 16640
#define X2_STR   1040
#define X3_OFF   X1_OFF   // alias over X1 (dead after conv2b): bf16 [8][8][32] stride 528
#define X3_STR   528
#define X4_OFF   (X1_OFF + 4224)   // bf16 [4][4][32] stride 272 -> 1088
#define X4_STR   272
#define X5_OFF   (X1_OFF + 5312)   // bf16 [2][2][32] stride 144 -> 288
#define X5_STR   144
#define X6_OFF   (X1_OFF + 5600)   // 32 f32 = 128
#define SMEM_BYTES 69664
// All X accesses swizzled: byte_bit4 ^= buffer_row_bit3; out-of-range taps read
// the zero page. R8 lesson: 512-thread blocks at VGPR 116 can't co-schedule
// (16 waves x 116 regs over budget; R7's VGPR-64 did = 46.7% occ). 256-thread
// blocks need only 8 waves x 116 for 2 blocks/CU -> two independent barrier
// domains overlap each other's stalls.

__device__ __forceinline__ unsigned short f2bf(float f) {   // RNE f32->bf16
    unsigned int x = __float_as_uint(f);
    x += 0x7fffu + ((x >> 16) & 1u);
    return (unsigned short)(x >> 16);
}

// B-frags for mfma_f32_16x16x32_bf16 (VERIFIED mapping, Round 2):
// lane l: col n=l&15 (co = nt*16+n), k = (l>>4)*8 + e.  ws: bf16 [L][tap][co][ci].
__device__ __forceinline__ void loadB16(short8 bfr[16], const unsigned short* __restrict__ wsbf,
                                        const float* __restrict__ rwg, int useWs,
                                        int L, int co, int g) {
    if (useWs) {
        const unsigned short* base = wsbf + L * 16384 + co * 32 + g * 8;
#pragma unroll
        for (int tap = 0; tap < 16; ++tap)
            bfr[tap] = *(const short8*)(base + tap * 1024);
    } else {  // fallback: gather f32 weights from rwg [L][co][ci][tap], convert in regs
#pragma unroll
        for (int tap = 0; tap < 16; ++tap) {
            union { short8 s; unsigned short u[8]; } cv;
#pragma unroll
            for (int e = 0; e < 8; ++e)
                cv.u[e] = f2bf(rwg[((L * 32 + co) * 32 + g * 8 + e) * 16 + tap]);
            bfr[tap] = cv.s;
        }
    }
}

// One conv layer as 16 tap-GEMMs via mfma_f32_16x16x32_bf16 (Round-2-verified
// mappings). Output PH x QW spatial block (rows offset by p0), m = q*PH + p.
// Input: logical NIN x NIN halo-free tensor; buffer row = logical row - shift.
// Out-of-range taps read the zero page. All addrs swizzled: bit4 ^= row bit3.
template<int PH, int QW, int NIN, int INS, int OUTS, bool LAST>
__device__ __forceinline__ void convL(char* smb, int inOff, int outOff,
                                      const short8 bfr[16], float bias,
                                      int p0, int shift) {
    const int t = threadIdx.x;
    const int w = t >> 6, l = t & 63;
    const int n = l & 15, g = l >> 4, nt = w & 1;
    constexpr int M = PH * QW;
    constexpr int MT = (M + 15) / 16;
    for (int tile = w; tile < 2 * MT; tile += NW) {   // step NW (even) keeps tile&1 == nt
        const int mt = tile >> 1;
        f32x4 acc = {bias, bias, bias, bias};
        const int m = mt * 16 + (l & 15);
        const int mm = (m < M) ? m : 0;
        const int p = mm % PH, q = mm / PH;
#pragma unroll
        for (int a = 0; a < 4; ++a)
#pragma unroll
            for (int dj = 0; dj < 4; ++dj) {
                const int row = 2 * (p0 + p) + a - 1;       // logical coords
                const int col = 2 * q + dj - 1;
                const bool ok = (m < M) && ((unsigned)row < (unsigned)NIN)
                                        && ((unsigned)col < (unsigned)NIN);
                const int rb = row - shift;                  // buffer row
                unsigned addr = (unsigned)(inOff + rb * INS + col * 64 + g * 16);
                addr ^= (unsigned)(((rb >> 3) & 1) << 4);
                addr = ok ? addr : (unsigned)(ZP_OFF + g * 16);
                short8 af = *(const short8*)(smb + addr);
                acc = __builtin_amdgcn_mfma_f32_16x16x32_bf16(af, bfr[a * 4 + dj], acc, 0, 0, 0);
            }
#pragma unroll
        for (int vi = 0; vi < 4; ++vi) {                     // D: col=l&15, row=g*4+vi
            const int mo = mt * 16 + g * 4 + vi;
            if (mo < M) {
                const float v = fmaxf(acc[vi], 0.f);
                if constexpr (LAST) {                        // M==1: only mo==0 lands here
                    *(float*)(smb + outOff + (nt * 16 + n) * 4) = v;
                } else {
                    const int po = mo % PH + p0, qo = mo / PH;
                    unsigned addr = (unsigned)(outOff + po * OUTS + qo * 64 + (nt * 16 + n) * 2);
                    addr ^= (unsigned)(((po >> 3) & 1) << 4);
                    *(unsigned short*)(smb + addr) = f2bf(v);
                }
            }
        }
    }
}

// pre-convert rest_w (f32 [L][co][ci][a][dj]) -> d_ws bf16 [L][tap][co][ci]
__global__ void preconv_w(const float* __restrict__ rwg, unsigned short* __restrict__ wsbf) {
    int idx = blockIdx.x * 256 + threadIdx.x;
    if (idx < 81920) {
        int ci = idx & 31, co = (idx >> 5) & 31, tap = (idx >> 10) & 15, L = idx >> 14;
        wsbf[idx] = f2bf(rwg[(((L * 32 + co) * 32 + ci) << 4) + tap]);
    }
}

__global__ void __launch_bounds__(NT, 2)
convncf_main(const int* __restrict__ user, const int* __restrict__ item_pos,
             const int* __restrict__ item_neg,
             const float* __restrict__ uemb, const float* __restrict__ iemb,
             const float* __restrict__ w1g, const float* __restrict__ b1g,
             const float* __restrict__ rwg, const float* __restrict__ rbg,
             const float* __restrict__ pwg, const float* __restrict__ pbg,
             const unsigned short* __restrict__ wsbf, int useWs,
             float* __restrict__ out, int B)
{
    extern __shared__ char smb[];
    float* smf = (float*)smb;
    const int t = threadIdx.x, w = t >> 6, l = t & 63;
    const int co = ((t >> 6) & 1) * 16 + (t & 15);   // this thread's output channel
    const int g = l >> 4;
    const int s = blockIdx.x, branch = blockIdx.y;
    const int uidx = user[s];
    const int iidx = branch ? item_neg[s] : item_pos[s];

    short8 bfr[16];
    loadB16(bfr, wsbf, rwg, useWs, 0, co, g);   // conv2 weights: hide under P0-P2a

    // ---- P0: consts + embeddings + zero page (strided loop: 353 items, NT=256) ----
    for (int i = t; i < 353; i += NT) {
        if (i < 64)       smf[U_OFF/4 + i]        = uemb[(long)uidx * 64 + i];
        else if (i < 128) smf[IT_OFF/4 + i - 64]  = iemb[(long)iidx * 64 + i - 64];
        else if (i < 160) smf[B1_OFF/4 + i - 128] = b1g[i - 128];
        else if (i < 320) smf[RB_OFF/4 + i - 160] = rbg[i - 160];
        else if (i < 352) smf[PW_OFF/4 + i - 320] = pwg[i - 320];
        else              smf[PBI_OFF/4] = pbg[0];
    }
    if (t < 4) *(float4*)(smb + ZP_OFF + t * 16) = make_float4(0.f, 0.f, 0.f, 0.f);
    __syncthreads();

    // ---- P1: T[a][j][ci] = sum_dj w1[ci,a,dj] * it_pad[2j-1+dj] ----
    for (int v = t; v < 4096; v += NT) {
        const int ci = v & 31, j = (v >> 5) & 31, a = v >> 10;
        const float4 wv = *(const float4*)(w1g + ci * 16 + a * 4);
        const int c0 = 2 * j - 1;
        const float i0 = (c0 >= 0) ? smf[IT_OFF/4 + c0] : 0.f;
        const float i1 = smf[IT_OFF/4 + c0 + 1];
        const float i2 = smf[IT_OFF/4 + c0 + 2];
        const float i3 = (c0 + 3 < 64) ? smf[IT_OFF/4 + c0 + 3] : 0.f;
        float acc = wv.x * i0;
        acc = fmaf(wv.y, i1, acc);
        acc = fmaf(wv.z, i2, acc);
        acc = fmaf(wv.w, i3, acc);
        *(float*)(smb + T_OFF + (a * 32 + j) * 128 + ci * 4) = acc;
    }
    __syncthreads();

    // ---- two half-strips: build X1 rows, conv2 on matching output rows ----
#pragma unroll 1
    for (int h = 0; h < 2; ++h) {
        const int shift = 15 * h;
        // P2(h): X1buf rows rl=0..16 hold logical rows r=rl+shift (bf16, swizzled)
        for (int v = t; v < 2176; v += NT) {
            const int cg = v & 3, j = (v >> 2) & 31, rl = v >> 7;   // rl 0..16
            const int r = rl + shift;
            float acc[8];
            {
                const float* b1p = smf + B1_OFF/4 + cg * 8;
#pragma unroll
                for (int e = 0; e < 8; ++e) acc[e] = b1p[e];
            }
#pragma unroll
            for (int a = 0; a < 4; ++a) {
                const int m = 2 * r - 1 + a;
                const float uv = (m >= 0 && m < 64) ? smf[U_OFF/4 + m] : 0.f;
                const float* tp = (const float*)(smb + T_OFF + (a * 32 + j) * 128 + cg * 32);
                const float4 t0 = *(const float4*)tp;
                const float4 t1 = *(const float4*)(tp + 4);
                acc[0] = fmaf(uv, t0.x, acc[0]); acc[1] = fmaf(uv, t0.y, acc[1]);
                acc[2] = fmaf(uv, t0.z, acc[2]); acc[3] = fmaf(uv, t0.w, acc[3]);
                acc[4] = fmaf(uv, t1.x, acc[4]); acc[5] = fmaf(uv, t1.y, acc[5]);
                acc[6] = fmaf(uv, t1.z, acc[6]); acc[7] = fmaf(uv, t1.w, acc[7]);
            }
            union { short8 sv; unsigned short u[8]; } cv;
#pragma unroll
            for (int e = 0; e < 8; ++e) cv.u[e] = f2bf(fmaxf(acc[e], 0.f));
            unsigned addr = (unsigned)(X1_OFF + rl * X1_STR + j * 64 + cg * 16);
            addr ^= (unsigned)(((rl >> 3) & 1) << 4);
            *(short8*)(smb + addr) = cv.sv;
        }
        __syncthreads();

        // conv2(h): output rows p0..p0+7, all 16 cols
        convL<8, 16, 32, X1_STR, X2_STR, false>(smb, X1_OFF, X2_OFF, bfr,
                                                smf[RB_OFF/4 + co], 8 * h, shift);
        if (h == 1) loadB16(bfr, wsbf, rwg, useWs, 1, co, g);   // L0 frags dead now
        __syncthreads();
    }

    // ---- conv3..6; next layer's B-frags load before each barrier ----
    convL<8, 8, 16, X2_STR, X3_STR, false>(smb, X2_OFF, X3_OFF, bfr, smf[RB_OFF/4 + 32 + co], 0, 0);
    loadB16(bfr, wsbf, rwg, useWs, 2, co, g);
    __syncthreads();

    convL<4, 4, 8, X3_STR, X4_STR, false>(smb, X3_OFF, X4_OFF, bfr, smf[RB_OFF/4 + 64 + co], 0, 0);
    loadB16(bfr, wsbf, rwg, useWs, 3, co, g);
    __syncthreads();

    convL<2, 2, 4, X4_STR, X5_STR, false>(smb, X4_OFF, X5_OFF, bfr, smf[RB_OFF/4 + 96 + co], 0, 0);
    loadB16(bfr, wsbf, rwg, useWs, 4, co, g);
    __syncthreads();

    convL<1, 1, 2, X5_STR, 0, true>(smb, X5_OFF, X6_OFF, bfr, smf[RB_OFF/4 + 128 + co], 0, 0);
    __syncthreads();

    // ---- head: wave 0 dot(X6, pw) + sigmoid ----
    if (w == 0) {
        float v = (l < 32) ? smf[X6_OFF/4 + l] * smf[PW_OFF/4 + l] : 0.f;
#pragma unroll
        for (int d = 32; d >= 1; d >>= 1) v += __shfl_xor(v, d, 64);
        if (l == 0) {
            const float z = smf[PBI_OFF/4] + v;
            out[branch * B + s] = 1.f / (1.f + expf(-z));
        }
    }
}

extern "C" void kernel_launch(void* const* d_in, const int* in_sizes, int n_in,
                              void* d_out, int out_size, void* d_ws, size_t ws_size,
                              hipStream_t stream) {
    const int*   user     = (const int*)d_in[0];
    const int*   item_pos = (const int*)d_in[1];
    const int*   item_neg = (const int*)d_in[2];
    const float* uemb     = (const float*)d_in[3];
    const float* iemb     = (const float*)d_in[4];
    const float* w1       = (const float*)d_in[5];
    const float* b1       = (const float*)d_in[6];
    const float* rw       = (const float*)d_in[7];
    const float* rb       = (const float*)d_in[8];
    const float* pw       = (const float*)d_in[9];
    const float* pb       = (const float*)d_in[10];
    float* out = (float*)d_out;
    const int B = in_sizes[0];   // 4096

    const int useWs = (ws_size >= 81920u * sizeof(unsigned short)) ? 1 : 0;
    unsigned short* wsbf = (unsigned short*)d_ws;
    if (useWs)
        preconv_w<<<dim3(320), dim3(256), 0, stream>>>(rw, wsbf);

    (void)hipFuncSetAttribute((const void*)convncf_main,
                              hipFuncAttributeMaxDynamicSharedMemorySize, SMEM_BYTES);
    dim3 grid(B, 2);
    convncf_main<<<grid, NT, SMEM_BYTES, stream>>>(
        user, item_pos, item_neg, uemb, iemb, w1, b1, rw, rb, pw, pb,
        wsbf, useWs, out, B);
}

// Round 10
// 329.357 us; speedup vs baseline: 2.2641x; 1.1420x over previous
//
#include <hip/hip_runtime.h>
#include <math.h>

#define NT 256
#define NW 4

typedef __attribute__((ext_vector_type(8))) short short8;
typedef __attribute__((ext_vector_type(4))) float f32x4;

// ---- LDS arena byte offsets (total 71,696 B; 2 blocks/CU) ----
#define U_OFF    0        // 64 f32
#define IT_OFF   256      // 64 f32
#define B1_OFF   512      // 32 f32
#define RB_OFF   640      // 160 f32
#define PW_OFF   1280     // 32 f32
#define PBI_OFF  1408     // 1 f32
#define ZP_OFF   1424     // 64 B zero page (predicated out-of-range reads land here)
#define X1_OFF   1536     // bf16 [17][32][32] stride 2064 -> 35088 (two-half strip of conv1 out)
#define X1_STR   2064
#define T_OFF    36624    // f32 [4][32][ci32] stride 144 (+16B pad: bank-conflict-free reads)
#define X2_OFF   55056    // bf16 [16][16][32] stride 1040 -> 16640
#define X2_STR   1040
#define X3_OFF   X1_OFF   // alias over X1 (dead after conv2b): bf16 [8][8][32] stride 528
#define X3_STR   528
#define X4_OFF   (X1_OFF + 4224)   // bf16 [4][4][32] stride 272 -> 1088
#define X4_STR   272
#define X5_OFF   (X1_OFF + 5312)   // bf16 [2][2][32] stride 144 -> 288
#define X5_STR   144
#define X6_OFF   (X1_OFF + 5600)   // 32 f32 = 128
#define SMEM_BYTES 71696
// All X accesses swizzled: byte_bit4 ^= buffer_row_bit3 (16B pad per row is the
// swap space). R9 lesson: LDS pipe is the shared bottleneck (~70% busy); T at
// stride 128 made P2's T-reads a 16-way bank conflict (j-stride 128B). Fix:
// stride 144 -> bank (4j+8cg)%32, disjoint 4-bank groups, conflict-free; and
// P2 restructured so T is read ONCE per thread (hoisted), not once per row.

__device__ __forceinline__ unsigned short f2bf(float f) {   // RNE f32->bf16
    unsigned int x = __float_as_uint(f);
    x += 0x7fffu + ((x >> 16) & 1u);
    return (unsigned short)(x >> 16);
}

// B-frags for mfma_f32_16x16x32_bf16 (VERIFIED mapping, Round 2):
// lane l: col n=l&15 (co = nt*16+n), k = (l>>4)*8 + e.  ws: bf16 [L][tap][co][ci].
__device__ __forceinline__ void loadB16(short8 bfr[16], const unsigned short* __restrict__ wsbf,
                                        const float* __restrict__ rwg, int useWs,
                                        int L, int co, int g) {
    if (useWs) {
        const unsigned short* base = wsbf + L * 16384 + co * 32 + g * 8;
#pragma unroll
        for (int tap = 0; tap < 16; ++tap)
            bfr[tap] = *(const short8*)(base + tap * 1024);
    } else {  // fallback: gather f32 weights from rwg [L][co][ci][tap], convert in regs
#pragma unroll
        for (int tap = 0; tap < 16; ++tap) {
            union { short8 s; unsigned short u[8]; } cv;
#pragma unroll
            for (int e = 0; e < 8; ++e)
                cv.u[e] = f2bf(rwg[((L * 32 + co) * 32 + g * 8 + e) * 16 + tap]);
            bfr[tap] = cv.s;
        }
    }
}

// One conv layer as 16 tap-GEMMs via mfma_f32_16x16x32_bf16 (Round-2-verified
// mappings). Output PH x QW spatial block (rows offset by p0), m = q*PH + p.
// Input: logical NIN x NIN halo-free tensor; buffer row = logical row - shift.
// Out-of-range taps read the zero page. All addrs swizzled: bit4 ^= row bit3.
template<int PH, int QW, int NIN, int INS, int OUTS, bool LAST>
__device__ __forceinline__ void convL(char* smb, int inOff, int outOff,
                                      const short8 bfr[16], float bias,
                                      int p0, int shift) {
    const int t = threadIdx.x;
    const int w = t >> 6, l = t & 63;
    const int n = l & 15, g = l >> 4, nt = w & 1;
    constexpr int M = PH * QW;
    constexpr int MT = (M + 15) / 16;
    for (int tile = w; tile < 2 * MT; tile += NW) {   // step NW (even) keeps tile&1 == nt
        const int mt = tile >> 1;
        f32x4 acc = {bias, bias, bias, bias};
        const int m = mt * 16 + (l & 15);
        const int mm = (m < M) ? m : 0;
        const int p = mm % PH, q = mm / PH;
#pragma unroll
        for (int a = 0; a < 4; ++a)
#pragma unroll
            for (int dj = 0; dj < 4; ++dj) {
                const int row = 2 * (p0 + p) + a - 1;       // logical coords
                const int col = 2 * q + dj - 1;
                const bool ok = (m < M) && ((unsigned)row < (unsigned)NIN)
                                        && ((unsigned)col < (unsigned)NIN);
                const int rb = row - shift;                  // buffer row
                unsigned addr = (unsigned)(inOff + rb * INS + col * 64 + g * 16);
                addr ^= (unsigned)(((rb >> 3) & 1) << 4);
                addr = ok ? addr : (unsigned)(ZP_OFF + g * 16);
                short8 af = *(const short8*)(smb + addr);
                acc = __builtin_amdgcn_mfma_f32_16x16x32_bf16(af, bfr[a * 4 + dj], acc, 0, 0, 0);
            }
#pragma unroll
        for (int vi = 0; vi < 4; ++vi) {                     // D: col=l&15, row=g*4+vi
            const int mo = mt * 16 + g * 4 + vi;
            if (mo < M) {
                const float v = fmaxf(acc[vi], 0.f);
                if constexpr (LAST) {                        // M==1: only mo==0 lands here
                    *(float*)(smb + outOff + (nt * 16 + n) * 4) = v;
                } else {
                    const int po = mo % PH + p0, qo = mo / PH;
                    unsigned addr = (unsigned)(outOff + po * OUTS + qo * 64 + (nt * 16 + n) * 2);
                    addr ^= (unsigned)(((po >> 3) & 1) << 4);
                    *(unsigned short*)(smb + addr) = f2bf(v);
                }
            }
        }
    }
}

// pre-convert rest_w (f32 [L][co][ci][a][dj]) -> d_ws bf16 [L][tap][co][ci]
__global__ void preconv_w(const float* __restrict__ rwg, unsigned short* __restrict__ wsbf) {
    int idx = blockIdx.x * 256 + threadIdx.x;
    if (idx < 81920) {
        int ci = idx & 31, co = (idx >> 5) & 31, tap = (idx >> 10) & 15, L = idx >> 14;
        wsbf[idx] = f2bf(rwg[(((L * 32 + co) * 32 + ci) << 4) + tap]);
    }
}

__global__ void __launch_bounds__(NT, 2)
convncf_main(const int* __restrict__ user, const int* __restrict__ item_pos,
             const int* __restrict__ item_neg,
             const float* __restrict__ uemb, const float* __restrict__ iemb,
             const float* __restrict__ w1g, const float* __restrict__ b1g,
             const float* __restrict__ rwg, const float* __restrict__ rbg,
             const float* __restrict__ pwg, const float* __restrict__ pbg,
             const unsigned short* __restrict__ wsbf, int useWs,
             float* __restrict__ out, int B)
{
    extern __shared__ char smb[];
    float* smf = (float*)smb;
    const int t = threadIdx.x, w = t >> 6, l = t & 63;
    const int co = ((t >> 6) & 1) * 16 + (t & 15);   // this thread's output channel
    const int g = l >> 4;
    const int s = blockIdx.x, branch = blockIdx.y;
    const int uidx = user[s];
    const int iidx = branch ? item_neg[s] : item_pos[s];

    short8 bfr[16];
    loadB16(bfr, wsbf, rwg, useWs, 0, co, g);   // conv2 weights: hide under P0-P2a

    // ---- P0: consts + embeddings + zero page (strided loop: 353 items) ----
    for (int i = t; i < 353; i += NT) {
        if (i < 64)       smf[U_OFF/4 + i]        = uemb[(long)uidx * 64 + i];
        else if (i < 128) smf[IT_OFF/4 + i - 64]  = iemb[(long)iidx * 64 + i - 64];
        else if (i < 160) smf[B1_OFF/4 + i - 128] = b1g[i - 128];
        else if (i < 320) smf[RB_OFF/4 + i - 160] = rbg[i - 160];
        else if (i < 352) smf[PW_OFF/4 + i - 320] = pwg[i - 320];
        else              smf[PBI_OFF/4] = pbg[0];
    }
    if (t < 4) *(float4*)(smb + ZP_OFF + t * 16) = make_float4(0.f, 0.f, 0.f, 0.f);
    __syncthreads();

    // ---- P1: T[a][j][ci] = sum_dj w1[ci,a,dj] * it_pad[2j-1+dj] (stride 144) ----
    for (int v = t; v < 4096; v += NT) {
        const int ci = v & 31, j = (v >> 5) & 31, a = v >> 10;
        const float4 wv = *(const float4*)(w1g + ci * 16 + a * 4);
        const int c0 = 2 * j - 1;
        const float i0 = (c0 >= 0) ? smf[IT_OFF/4 + c0] : 0.f;
        const float i1 = smf[IT_OFF/4 + c0 + 1];
        const float i2 = smf[IT_OFF/4 + c0 + 2];
        const float i3 = (c0 + 3 < 64) ? smf[IT_OFF/4 + c0 + 3] : 0.f;
        float acc = wv.x * i0;
        acc = fmaf(wv.y, i1, acc);
        acc = fmaf(wv.z, i2, acc);
        acc = fmaf(wv.w, i3, acc);
        *(float*)(smb + T_OFF + (a * 32 + j) * 144 + ci * 4) = acc;
    }
    __syncthreads();

    // ---- P2+conv2, two half-strips. P2: thread owns (j, cg); T read ONCE
    //      (8 x ds_read_b128, conflict-free), u reads are wave-uniform
    //      broadcasts, rows looped in registers. ----
    {
        const int pi = t & 127;
        const int cgp = pi & 3, jp = pi >> 2;        // this thread's (col j, chan group)
        const int rlh = t >> 7;                      // row-half: 0 -> rl 0..8, 1 -> rl 9..16
        const int rl0 = rlh ? 9 : 0;
        const int rl1 = rlh ? 17 : 9;

        float4 tv[4][2];                             // hoisted T[a][jp][cgp*8..+7]
#pragma unroll
        for (int a = 0; a < 4; ++a) {
            const float* tp = (const float*)(smb + T_OFF + (a * 32 + jp) * 144 + cgp * 32);
            tv[a][0] = *(const float4*)tp;
            tv[a][1] = *(const float4*)(tp + 4);
        }
        float bb[8];
        {
            const float* b1p = smf + B1_OFF/4 + cgp * 8;
#pragma unroll
            for (int e = 0; e < 8; ++e) bb[e] = b1p[e];
        }

#pragma unroll 1
        for (int h = 0; h < 2; ++h) {
            const int shift = 15 * h;
            for (int rl = rl0; rl < rl1; ++rl) {
                const int r = rl + shift;
                float acc[8];
#pragma unroll
                for (int e = 0; e < 8; ++e) acc[e] = bb[e];
#pragma unroll
                for (int a = 0; a < 4; ++a) {
                    const int m = 2 * r - 1 + a;
                    const float uv = (m >= 0 && m < 64) ? smf[U_OFF/4 + m] : 0.f;
                    acc[0] = fmaf(uv, tv[a][0].x, acc[0]);
                    acc[1] = fmaf(uv, tv[a][0].y, acc[1]);
                    acc[2] = fmaf(uv, tv[a][0].z, acc[2]);
                    acc[3] = fmaf(uv, tv[a][0].w, acc[3]);
                    acc[4] = fmaf(uv, tv[a][1].x, acc[4]);
                    acc[5] = fmaf(uv, tv[a][1].y, acc[5]);
                    acc[6] = fmaf(uv, tv[a][1].z, acc[6]);
                    acc[7] = fmaf(uv, tv[a][1].w, acc[7]);
                }
                union { short8 sv; unsigned short u[8]; } cv;
#pragma unroll
                for (int e = 0; e < 8; ++e) cv.u[e] = f2bf(fmaxf(acc[e], 0.f));
                unsigned addr = (unsigned)(X1_OFF + rl * X1_STR + jp * 64 + cgp * 16);
                addr ^= (unsigned)(((rl >> 3) & 1) << 4);
                *(short8*)(smb + addr) = cv.sv;
            }
            __syncthreads();

            // conv2(h): output rows 8h..8h+7, all 16 cols
            convL<8, 16, 32, X1_STR, X2_STR, false>(smb, X1_OFF, X2_OFF, bfr,
                                                    smf[RB_OFF/4 + co], 8 * h, shift);
            if (h == 1) loadB16(bfr, wsbf, rwg, useWs, 1, co, g);   // L0 frags dead now
            __syncthreads();
        }
    }

    // ---- conv3..6; next layer's B-frags load before each barrier ----
    convL<8, 8, 16, X2_STR, X3_STR, false>(smb, X2_OFF, X3_OFF, bfr, smf[RB_OFF/4 + 32 + co], 0, 0);
    loadB16(bfr, wsbf, rwg, useWs, 2, co, g);
    __syncthreads();

    convL<4, 4, 8, X3_STR, X4_STR, false>(smb, X3_OFF, X4_OFF, bfr, smf[RB_OFF/4 + 64 + co], 0, 0);
    loadB16(bfr, wsbf, rwg, useWs, 3, co, g);
    __syncthreads();

    convL<2, 2, 4, X4_STR, X5_STR, false>(smb, X4_OFF, X5_OFF, bfr, smf[RB_OFF/4 + 96 + co], 0, 0);
    loadB16(bfr, wsbf, rwg, useWs, 4, co, g);
    __syncthreads();

    convL<1, 1, 2, X5_STR, 0, true>(smb, X5_OFF, X6_OFF, bfr, smf[RB_OFF/4 + 128 + co], 0, 0);
    __syncthreads();

    // ---- head: wave 0 dot(X6, pw) + sigmoid ----
    if (w == 0) {
        float v = (l < 32) ? smf[X6_OFF/4 + l] * smf[PW_OFF/4 + l] : 0.f;
#pragma unroll
        for (int d = 32; d >= 1; d >>= 1) v += __shfl_xor(v, d, 64);
        if (l == 0) {
            const float z = smf[PBI_OFF/4] + v;
            out[branch * B + s] = 1.f / (1.f + expf(-z));
        }
    }
}

extern "C" void kernel_launch(void* const* d_in, const int* in_sizes, int n_in,
                              void* d_out, int out_size, void* d_ws, size_t ws_size,
                              hipStream_t stream) {
    const int*   user     = (const int*)d_in[0];
    const int*   item_pos = (const int*)d_in[1];
    const int*   item_neg = (const int*)d_in[2];
    const float* uemb     = (const float*)d_in[3];
    const float* iemb     = (const float*)d_in[4];
    const float* w1       = (const float*)d_in[5];
    const float* b1       = (const float*)d_in[6];
    const float* rw       = (const float*)d_in[7];
    const float* rb       = (const float*)d_in[8];
    const float* pw       = (const float*)d_in[9];
    const float* pb       = (const float*)d_in[10];
    float* out = (float*)d_out;
    const int B = in_sizes[0];   // 4096

    const int useWs = (ws_size >= 81920u * sizeof(unsigned short)) ? 1 : 0;
    unsigned short* wsbf = (unsigned short*)d_ws;
    if (useWs)
        preconv_w<<<dim3(320), dim3(256), 0, stream>>>(rw, wsbf);

    (void)hipFuncSetAttribute((const void*)convncf_main,
                              hipFuncAttributeMaxDynamicSharedMemorySize, SMEM_BYTES);
    dim3 grid(B, 2);
    convncf_main<<<grid, NT, SMEM_BYTES, stream>>>(
        user, item_pos, item_neg, uemb, iemb, w1, b1, rw, rb, pw, pb,
        wsbf, useWs, out, B);
}